// Round 6
// baseline (95.539 us; speedup 1.0000x reference)
//
#include <hip/hip_runtime.h>
#include <hip/hip_bf16.h>

typedef __bf16 bf16x8 __attribute__((ext_vector_type(8)));
typedef __bf16 bf16x4 __attribute__((ext_vector_type(4)));
typedef float  f32x4  __attribute__((ext_vector_type(4)));
typedef int    int4v  __attribute__((ext_vector_type(4)));
typedef float  flt4v  __attribute__((ext_vector_type(4)));

#define ALPHA 0.2f
// B=8, N=2048, D=128. Inputs: h,W,a f32; adj int32. OUTPUT: float32 (reference returns f32!).

// Kernel A: Wh = bf16(h) @ bf16(W) via MFMA 16x16x32, stored TRANSPOSED wht[b][col][n] (bf16).
// Scores s_src/s_dst computed in PURE f32 as h · (W @ a) — exp amplifies score error.
__global__ __launch_bounds__(256) void gat_wh(
    const float* __restrict__ h,    // [8][2048][128] f32
    const float* __restrict__ W,    // [128][128] f32
    const float* __restrict__ a,    // [256] f32
    __bf16* __restrict__ wht,       // [8][128][2048] bf16
    float* __restrict__ ssrc,       // [8*2048]
    float* __restrict__ sdst)       // [8*2048]
{
    __shared__ __bf16 Wt[128][136];       // W transposed (bf16), padded
    __shared__ float wvs[128], wvd[128];  // W @ a_src, W @ a_dst (f32)
    const int tid = threadIdx.x;
    if (tid < 128) {
        float s0 = 0.f, s1 = 0.f;
        const float* wr = W + tid * 128;
        #pragma unroll 4
        for (int e = 0; e < 128; ++e) {
            float w = wr[e];
            s0 += w * a[e];
            s1 += w * a[128 + e];
        }
        wvs[tid] = s0; wvd[tid] = s1;
    }
    #pragma unroll
    for (int it = 0; it < 8; ++it) {
        int o = (it * 256 + tid) * 8;            // element offset in W
        flt4v v0 = *reinterpret_cast<const flt4v*>(W + o);
        flt4v v1 = *reinterpret_cast<const flt4v*>(W + o + 4);
        int d = o >> 7, e = o & 127;             // d = row(k), e = col base
        #pragma unroll
        for (int j = 0; j < 4; ++j) {
            Wt[e + j][d]     = (__bf16)v0[j];
            Wt[e + 4 + j][d] = (__bf16)v1[j];
        }
    }
    __syncthreads();
    const int wave = tid >> 6, lane = tid & 63;
    const int lr = lane & 15, lg = lane >> 4;
    const int row0 = blockIdx.x * 64 + wave * 16;   // flattened (b*2048+n) row base
    f32x4 acc[8];
    #pragma unroll
    for (int ct = 0; ct < 8; ++ct) acc[ct] = (f32x4){0.f, 0.f, 0.f, 0.f};
    #pragma unroll
    for (int kk = 0; kk < 4; ++kk) {
        // A frag: A[m=lr][k=kk*32+lg*8+u], f32 -> bf16
        const float* hp = h + (size_t)(row0 + lr) * 128 + kk * 32 + lg * 8;
        flt4v h0 = *reinterpret_cast<const flt4v*>(hp);
        flt4v h1 = *reinterpret_cast<const flt4v*>(hp + 4);
        bf16x8 af;
        #pragma unroll
        for (int j = 0; j < 4; ++j) { af[j] = (__bf16)h0[j]; af[4 + j] = (__bf16)h1[j]; }
        #pragma unroll
        for (int ct = 0; ct < 8; ++ct) {
            // B frag: B[k][n=ct*16+lr] = W[k][col] = Wt[col][k]
            bf16x8 bf_ = *reinterpret_cast<const bf16x8*>(&Wt[ct * 16 + lr][kk * 32 + lg * 8]);
            acc[ct] = __builtin_amdgcn_mfma_f32_16x16x32_bf16(af, bf_, acc[ct], 0, 0, 0);
        }
    }
    // D layout: row = lg*4+q, col = ct*16+lr  -> store transposed (4 consecutive n per lane)
    const int b  = row0 >> 11;
    const int n0 = row0 & 2047;
    __bf16* wb = wht + (size_t)b * 128 * 2048;
    #pragma unroll
    for (int ct = 0; ct < 8; ++ct) {
        bf16x4 v;
        #pragma unroll
        for (int q = 0; q < 4; ++q) v[q] = (__bf16)acc[ct][q];
        *reinterpret_cast<bf16x4*>(wb + (ct * 16 + lr) * 2048 + n0 + lg * 4) = v;
    }
    // f32 scores: lane (lg,lr) covers row (row0+lr), cols lg*32..lg*32+31
    const float* hrow = h + (size_t)(row0 + lr) * 128 + lg * 32;
    float s0 = 0.f, s1 = 0.f;
    #pragma unroll
    for (int u = 0; u < 32; u += 4) {
        flt4v hv = *reinterpret_cast<const flt4v*>(hrow + u);
        #pragma unroll
        for (int q = 0; q < 4; ++q) {
            float x = hv[q];
            s0 += x * wvs[lg * 32 + u + q];
            s1 += x * wvd[lg * 32 + u + q];
        }
    }
    s0 += __shfl_xor(s0, 16, 64); s0 += __shfl_xor(s0, 32, 64);
    s1 += __shfl_xor(s1, 16, 64); s1 += __shfl_xor(s1, 32, 64);
    if (lg == 0) {
        ssrc[row0 + lr] = s0;
        sdst[row0 + lr] = s1;
    }
}

// Kernel C: fused masked-softmax attention + PV. OUTPUT F32.
// Grid: 1024 blocks = 8 batches * 128 row-tiles of 16. Block: 256 thr = 4 waves,
// all waves share the same 16 rows; j-tiles (64 wide) split 4-ways across waves.
// No online max (scores bounded): p = exp(lrelu(si+sj)) * mask; partials merge additively.
__global__ __launch_bounds__(256, 4) void gat_attn(
    const int* __restrict__ adj,            // [8][2048][2048]
    const __bf16* __restrict__ wht,         // [8][128][2048] bf16
    const float* __restrict__ ssrc,
    const float* __restrict__ sdst,
    float* __restrict__ out)                // [8][2048][128] f32
{
    __shared__ float accsh[4][16][128];
    __shared__ float lsh[4][16];
    const int tid = threadIdx.x, wave = tid >> 6, lane = tid & 63;
    const int lr = lane & 15, lg = lane >> 4;
    const int b  = blockIdx.x >> 7;
    const int i0 = (blockIdx.x & 127) << 4;
    const int row = i0 + lr;                       // this lane's P-row (A-frag row)
    const float si = ssrc[b * 2048 + row];
    const int* adjrow = adj + ((size_t)b * 2048 + row) * 2048;
    const float* sd = sdst + b * 2048;
    const __bf16* wb = wht + (size_t)b * 128 * 2048;

    f32x4 acc[8];
    #pragma unroll
    for (int ct = 0; ct < 8; ++ct) acc[ct] = (f32x4){0.f, 0.f, 0.f, 0.f};
    float lpart = 0.f;

    for (int jt = wave; jt < 32; jt += 4) {
        const int j0 = jt * 64;
        bf16x8 pf[2];
        #pragma unroll
        for (int kk = 0; kk < 2; ++kk) {
            const int jb = j0 + kk * 32 + lg * 8;  // this lane's 8 j's for this k-chunk
            #pragma unroll
            for (int v = 0; v < 2; ++v) {
                int4v av = *reinterpret_cast<const int4v*>(adjrow + jb + v * 4);
                flt4v sv = *reinterpret_cast<const flt4v*>(sd + jb + v * 4);
                #pragma unroll
                for (int u = 0; u < 4; ++u) {
                    float e = si + sv[u];
                    e = fmaxf(e, ALPHA * e);           // leaky_relu (slope<1)
                    float p = __expf(e);
                    p = (av[u] != 0) ? p : 0.f;
                    __bf16 pb = (__bf16)p;
                    lpart += (float)pb;                // denom matches bf16 numerator
                    pf[kk][v * 4 + u] = pb;
                }
            }
        }
        #pragma unroll
        for (int kk = 0; kk < 2; ++kk) {
            const int jb = j0 + kk * 32 + lg * 8;
            #pragma unroll
            for (int ct = 0; ct < 8; ++ct) {
                // B frag: B[k=lg*8+u][n=ct*16+lr] = Wh[jb+u][ct*16+lr] = wht[ct*16+lr][jb+u]
                bf16x8 bf_ = *reinterpret_cast<const bf16x8*>(wb + (ct * 16 + lr) * 2048 + jb);
                acc[ct] = __builtin_amdgcn_mfma_f32_16x16x32_bf16(pf[kk], bf_, acc[ct], 0, 0, 0);
            }
        }
    }
    // reduce l over the 4 k-groups (lanes lr, lr+16, lr+32, lr+48)
    lpart += __shfl_xor(lpart, 16, 64);
    lpart += __shfl_xor(lpart, 32, 64);
    if (lane < 16) lsh[wave][lr] = lpart;
    #pragma unroll
    for (int ct = 0; ct < 8; ++ct) {
        #pragma unroll
        for (int q = 0; q < 4; ++q)
            accsh[wave][lg * 4 + q][ct * 16 + lr] = acc[ct][q];
    }
    __syncthreads();
    // merge 4 wave-partials and write out (F32)
    float* ob = out + ((size_t)b * 2048 + i0) * 128;
    #pragma unroll
    for (int it = 0; it < 8; ++it) {
        int o = it * 256 + tid;
        int r = o >> 7, c2 = o & 127;
        float vsum = accsh[0][r][c2] + accsh[1][r][c2] + accsh[2][r][c2] + accsh[3][r][c2];
        float l = lsh[0][r] + lsh[1][r] + lsh[2][r] + lsh[3][r];
        ob[r * 128 + c2] = vsum / l;
    }
}

extern "C" void kernel_launch(void* const* d_in, const int* in_sizes, int n_in,
                              void* d_out, int out_size, void* d_ws, size_t ws_size,
                              hipStream_t stream)
{
    // Bind inputs by element count (all four sizes distinct); fall back to dict order.
    const float* h = nullptr; const int* adj = nullptr;
    const float* W = nullptr; const float* a = nullptr;
    for (int i = 0; i < n_in; ++i) {
        switch (in_sizes[i]) {
            case 2097152:  h   = (const float*)d_in[i]; break;  // 8*2048*128
            case 33554432: adj = (const int*)d_in[i];   break;  // 8*2048*2048
            case 16384:    W   = (const float*)d_in[i]; break;  // 128*128
            case 256:      a   = (const float*)d_in[i]; break;  // 2*128
        }
    }
    if (!h || !adj || !W || !a) {
        h   = (const float*)d_in[0];
        adj = (const int*)d_in[1];
        W   = (const float*)d_in[2];
        a   = (const float*)d_in[3];
    }

    __bf16* wht = (__bf16*)d_ws;                                            // 4 MB (8*128*2048 bf16)
    float* ssrc = (float*)((char*)d_ws + (size_t)4 * 1024 * 1024);          // 64 KB
    float* sdst = ssrc + 8 * 2048;                                          // 64 KB

    gat_wh<<<256, 256, 0, stream>>>(h, W, a, wht, ssrc, sdst);
    gat_attn<<<1024, 256, 0, stream>>>(adj, wht, ssrc, sdst, (float*)d_out);
}